// Round 9
// baseline (283.546 us; speedup 1.0000x reference)
//
#include <hip/hip_runtime.h>
#include <math.h>

// ---------------------------------------------------------------------------
// EncoderGPECls: kNN(16) -> PCA curvature blend -> adaptive GPE embeddings
// xyz: [8,4096,3] f32  ->  out: [8,4096,128] f32
//
// R21 = R20 fused into ONE persistent kernel with a device-scope barrier.
//   R20 evidence: knn 198us but total-knn = ~47us constant across all
//   2-dispatch rounds (out_kernel floor is ~4us) -> the second dispatch,
//   its re-derived prefix, and the 524KB curv/rasig2 HBM round-trip are
//   pure overhead. Grid = 512 blocks at exactly 2 blocks/CU (LDS 75.7KB
//   <= 80KB, VGPR <= 128) = exact-fit co-residency on 256 CUs -> global
//   spin barrier is deadlock-free.
//   - Phase C (scan/select) identical to R20 (pass1 depth-8 ping-pong,
//     pass2 depth-4, u8 survivors, u16 merge publishes, exact semantics).
//   - Epilogue -> LDS (curv_l, r2l); csum & gstd via device-scope float
//     atomics (cross-XCD coherent); reference's gstd is a single GLOBAL
//     scalar over all 24 (batch,dim) stds -> one gsum accumulator.
//   - Barrier: tid0 atomicAdd counter, spin to 512, threadfence both sides.
//   - Phase E: block's own 64 queries x 128 outputs from LDS; 512 thr x 16
//     outputs; d-selects via ternaries (no runtime-indexed arrays); float4
//     stores fully coalesced.
//   Launch = 64B memsetAsync (ctr+atomics; graph-captured, replayed each
//   iteration) + 1 kernel.
//
// ws usage: ws[0] = u32 arrival counter; ws[1..8] = per-batch curv sums
//   (float atomics); ws[9] = global std sum (float atomic). 64B memset.
// ---------------------------------------------------------------------------

#define NPTS 4096
#define KNN 17          // 16 neighbors + self (self contributes zero to sums)
#define BLKT 512        // 8 waves; 64 queries per block (1 per lane)
#define QPB 64
#define ESIZE 512       // candidates per wave (eighth)
#define SEG 256         // pass-2 segment size (u8 offsets)
#define SCAP 17         // survivor slots per lane per segment
#define NBLK 512        // total blocks (must equal grid size; 2/CU x 256)

#define WS_CSA 1        // ws[1..8]: per-batch curv atomic sums
#define WS_GSA 9        // ws[9]: global std atomic sum

typedef unsigned long long ull;
#define SENT 0xFFFFFFFFFFFFFFFFULL

// THE single d2' definition: explicit fmaf chain, identical IEEE ops at every
// call site. c = (-2cx,-2cy,-2cz,|c|^2), q = original coords.
// d2'(c,q) = |c|^2 - 2 c.q = |c-q|^2 - |q|^2 (per-query constant offset ->
// identical ordering; can be negative). Self always ranks first.
__device__ __forceinline__ float d2p(float4 c, float qx, float qy, float qz) {
    return __builtin_fmaf(c.x, qx, __builtin_fmaf(c.y, qy,
           __builtin_fmaf(c.z, qz, c.w)));
}

// order-preserving u32 encoding of a (possibly negative) float
__device__ __forceinline__ unsigned encf(float f) {
    unsigned u = __float_as_uint(f);
    return u ^ (unsigned)(((int)u >> 31) | 0x80000000u);
}

// predicated replace-max insert of packed (enc(d2')<<32|idx) key
__device__ __forceinline__ void insertp(ull v, bool ins, ull (&md)[KNN],
                                        ull& maxv, int& maxp) {
#pragma unroll
    for (int k = 0; k < KNN; k++) {
        bool sel = ins && (k == maxp);
        md[k] = sel ? v : md[k];
    }
    maxv = md[0]; maxp = 0;
#pragma unroll
    for (int k = 1; k < KNN; k++) {
        bool g = md[k] > maxv;
        maxv = g ? md[k] : maxv;
        maxp = g ? k : maxp;
    }
}

// ---------------- 3x3 symmetric eigensolve (double, trig method) -----------
__device__ __forceinline__ float curv_from_cov(float c00, float c01, float c02,
                                               float c11, float c12, float c22) {
    double a00 = c00, a01 = c01, a02 = c02, a11 = c11, a12 = c12, a22 = c22;
    double tr = a00 + a11 + a22;
    double q  = tr * (1.0 / 3.0);
    double b00 = a00 - q, b11 = a11 - q, b22 = a22 - q;
    double p2 = b00 * b00 + b11 * b11 + b22 * b22
              + 2.0 * (a01 * a01 + a02 * a02 + a12 * a12);
    double lmin;
    if (p2 < 1e-60) {
        lmin = q;
    } else {
        double p  = sqrt(p2 * (1.0 / 6.0));
        double ip = 1.0 / p;
        double m00 = b00 * ip, m11 = b11 * ip, m22 = b22 * ip;
        double m01 = a01 * ip, m02 = a02 * ip, m12 = a12 * ip;
        double det = m00 * (m11 * m22 - m12 * m12)
                   - m01 * (m01 * m22 - m12 * m02)
                   + m02 * (m01 * m12 - m11 * m02);
        double r = 0.5 * det;
        r = r > 1.0 ? 1.0 : (r < -1.0 ? -1.0 : r);
        double phi = acos(r) * (1.0 / 3.0);
        lmin = q + 2.0 * p * cos(phi + 2.0943951023931953);
    }
    return (float)(lmin / (tr + 1e-6));
}

// ---------------- fused kNN + curvature + embedding ------------------------
__global__ __launch_bounds__(BLKT, 4) void fused_kernel(const float* __restrict__ xyz,
                                                        float* __restrict__ ws,
                                                        float* __restrict__ out) {
    __shared__ float4 pts[NPTS];                 // 64 KB premultiplied tile
    __shared__ ull aux[1088];                    // 8704 B arena (aliased)
    __shared__ double dstat[48];                 // chunk-0 stats scratch
    __shared__ float sc[4];                      // rasig1, blend, 1-b, cmean
    __shared__ float curv_l[QPB];                // per-query curvature
    __shared__ float r2l[3][QPB];                // per-query rasig2 (SoA)
    unsigned char* sbuf = (unsigned char*)aux;   // [SCAP][BLKT] u8 survivors
    unsigned short* pub = (unsigned short*)aux;  // 4 regions x 64x17 u16 idx

    int b = blockIdx.x >> 6;                     // 64 blocks per batch
    int chunk = blockIdx.x & 63;
    int tid = threadIdx.x;
    const float* base = xyz + b * NPTS * 3;
    for (int p = tid; p < NPTS; p += BLKT) {
        float x = base[p * 3], y = base[p * 3 + 1], z = base[p * 3 + 2];
        float w = __builtin_fmaf(z, z, __builtin_fmaf(y, y, x * x));
        pts[p] = make_float4(-2.0f * x, -2.0f * y, -2.0f * z, w);
    }
    __syncthreads();

    // ---- chunk-0 blocks: per-batch stds -> single global gsum atomic ------
    if (chunk == 0) {
        double sx = 0, sy = 0, sz = 0, qxx = 0, qyy = 0, qzz = 0;
        for (int p = tid; p < NPTS; p += BLKT) {
            float4 c = pts[p];
            float x = -0.5f * c.x, y = -0.5f * c.y, z = -0.5f * c.z; // exact
            sx += (double)x; sy += (double)y; sz += (double)z;
            qxx += (double)x * x; qyy += (double)y * y; qzz += (double)z * z;
        }
        for (int off = 32; off > 0; off >>= 1) {
            sx += __shfl_down(sx, off);  sy += __shfl_down(sy, off);
            sz += __shfl_down(sz, off);  qxx += __shfl_down(qxx, off);
            qyy += __shfl_down(qyy, off); qzz += __shfl_down(qzz, off);
        }
        int wid = tid >> 6;
        if ((tid & 63) == 0) {
            dstat[wid * 6 + 0] = sx;  dstat[wid * 6 + 1] = sy;  dstat[wid * 6 + 2] = sz;
            dstat[wid * 6 + 3] = qxx; dstat[wid * 6 + 4] = qyy; dstat[wid * 6 + 5] = qzz;
        }
        __syncthreads();
        if (tid == 0) {
            double S[6];
            for (int qq = 0; qq < 6; qq++) {
                double a = 0.0;
                for (int w = 0; w < 8; w++) a += dstat[w * 6 + qq];
                S[qq] = a;
            }
            double stds = 0.0;
            for (int dd = 0; dd < 3; dd++) {
                double var = (S[3 + dd] - S[dd] * S[dd] / 4096.0) / 4095.0;
                stds += sqrt(var > 0.0 ? var : 0.0);
            }
            atomicAdd(&ws[WS_GSA], (float)stds);
        }
    }

    int wv = tid >> 6;                           // wave id: candidate eighth
    int lane = tid & 63;
    int i = chunk * QPB + lane;                  // this lane's query point
    float4 qc = pts[i];
    float qx = -0.5f * qc.x, qy = -0.5f * qc.y, qz = -0.5f * qc.z;  // exact
    int cbase = wv * ESIZE;                      // this wave's candidate range

    // ---- pass 1: med3 top-17 ladder, depth-8 copy-free ping-pong ----------
    float md[KNN];
#pragma unroll
    for (int k = 0; k < KNN; k++) md[k] = 3.4e38f;

#define LADDER(c) { \
    float d2 = d2p((c), qx, qy, qz); \
    _Pragma("unroll") \
    for (int k = KNN - 1; k >= 1; k--) \
        md[k] = __builtin_amdgcn_fmed3f(d2, md[k - 1], md[k]); \
    md[0] = fminf(d2, md[0]); }

    {
        float4 A[8], B[8];
#pragma unroll
        for (int u = 0; u < 8; u++) A[u] = pts[cbase + u];
        for (int m = 0; m < ESIZE - 16; m += 16) {
#pragma unroll
            for (int u = 0; u < 8; u++) B[u] = pts[cbase + m + 8 + u];
#pragma unroll
            for (int u = 0; u < 8; u++) LADDER(A[u]);
#pragma unroll
            for (int u = 0; u < 8; u++) A[u] = pts[cbase + m + 16 + u];
#pragma unroll
            for (int u = 0; u < 8; u++) LADDER(B[u]);
        }
        // tail: A = [ESIZE-16, ESIZE-8)
#pragma unroll
        for (int u = 0; u < 8; u++) B[u] = pts[cbase + ESIZE - 8 + u];
#pragma unroll
        for (int u = 0; u < 8; u++) LADDER(A[u]);
#pragma unroll
        for (int u = 0; u < 8; u++) LADDER(B[u]);
    }
#undef LADDER
    float tau = md[KNN - 1];   // exact 17th (identical fmaf chain everywhere)

    // ---- pass 2 (2 segments of 256): u8 survivors, depth-4 ping-pong ------
    ull k17[KNN];
#pragma unroll
    for (int k = 0; k < KNN; k++) k17[k] = SENT;
    ull maxv = SENT; int maxp = 0;

#define P2BODY(c, off) { \
    float d2 = d2p((c), qx, qy, qz); \
    if (d2 <= tau) {                    /* clamp drops latest tie = jax */ \
        if (cnt < SCAP) sbuf[cnt * BLKT + tid] = (unsigned char)(off); \
        cnt++; } }

#pragma unroll
    for (int sgi = 0; sgi < 2; sgi++) {
        int segbase = cbase + sgi * SEG;
        int cnt = 0;
        {
            float4 A[4], B[4];
#pragma unroll
            for (int u = 0; u < 4; u++) A[u] = pts[segbase + u];
            for (int m = 0; m < SEG - 8; m += 8) {
#pragma unroll
                for (int u = 0; u < 4; u++) B[u] = pts[segbase + m + 4 + u];
#pragma unroll
                for (int u = 0; u < 4; u++) P2BODY(A[u], m + u);
#pragma unroll
                for (int u = 0; u < 4; u++) A[u] = pts[segbase + m + 8 + u];
#pragma unroll
                for (int u = 0; u < 4; u++) P2BODY(B[u], m + 4 + u);
            }
#pragma unroll
            for (int u = 0; u < 4; u++) B[u] = pts[segbase + SEG - 4 + u];
#pragma unroll
            for (int u = 0; u < 4; u++) P2BODY(A[u], SEG - 8 + u);
#pragma unroll
            for (int u = 0; u < 4; u++) P2BODY(B[u], SEG - 4 + u);
        }
        // drain this segment's survivors into the exact u64 top-17
#pragma unroll
        for (int t = 0; t < SCAP; t++) {
            if (__any(t < cnt)) {
                int ix = segbase + sbuf[t * BLKT + tid];
                float4 c = pts[ix];
                float d2 = d2p(c, qx, qy, qz);
                ull key = ((ull)encf(d2) << 32) | (unsigned)ix;
                bool ins = (t < cnt) && (key < maxv);
                if (__any(ins)) insertp(key, ins, k17, maxv, maxp);
            }
        }
    }
#undef P2BODY

    // ---- 3-round tournament merge (u16 idx publish, keys rebuilt exactly) --
    __syncthreads();
    if (wv & 1) {
#pragma unroll
        for (int k = 0; k < KNN; k++)
            pub[(wv >> 1) * 1088 + lane * KNN + k] = (unsigned short)(k17[k] & 0xffffULL);
    }
    __syncthreads();
    if (!(wv & 1)) {
        int r = wv >> 1;
#pragma unroll
        for (int k = 0; k < KNN; k++) {
            int ix = pub[r * 1088 + lane * KNN + k];
            float4 c = pts[ix];
            float d2 = d2p(c, qx, qy, qz);
            ull key = ((ull)encf(d2) << 32) | (unsigned)ix;
            bool ins = key < maxv;
            if (__any(ins)) insertp(key, ins, k17, maxv, maxp);
        }
    }
    // round 2: 2->0, 6->4 (regions 0,1)
    __syncthreads();
    if (wv == 2 || wv == 6) {
#pragma unroll
        for (int k = 0; k < KNN; k++)
            pub[(wv >> 2) * 1088 + lane * KNN + k] = (unsigned short)(k17[k] & 0xffffULL);
    }
    __syncthreads();
    if (wv == 0 || wv == 4) {
        int r = wv >> 2;
#pragma unroll
        for (int k = 0; k < KNN; k++) {
            int ix = pub[r * 1088 + lane * KNN + k];
            float4 c = pts[ix];
            float d2 = d2p(c, qx, qy, qz);
            ull key = ((ull)encf(d2) << 32) | (unsigned)ix;
            bool ins = key < maxv;
            if (__any(ins)) insertp(key, ins, k17, maxv, maxp);
        }
    }
    // round 3: 4->0 (region 0)
    __syncthreads();
    if (wv == 4) {
#pragma unroll
        for (int k = 0; k < KNN; k++)
            pub[lane * KNN + k] = (unsigned short)(k17[k] & 0xffffULL);
    }
    __syncthreads();

    // ---- epilogue on wave 0: final merge + moments -> curv, rasig2 (LDS) --
    if (wv == 0) {
#pragma unroll
        for (int k = 0; k < KNN; k++) {
            int ix = pub[lane * KNN + k];
            float4 c = pts[ix];
            float d2 = d2p(c, qx, qy, qz);
            ull key = ((ull)encf(d2) << 32) | (unsigned)ix;
            bool ins = key < maxv;
            if (__any(ins)) insertp(key, ins, k17, maxv, maxp);
        }

        float s1x = 0, s1y = 0, s1z = 0;
        float cxx = 0, cxy = 0, cxz = 0, cyy = 0, cyz = 0, czz = 0;
#pragma unroll
        for (int k = 0; k < KNN; k++) {
            int j = (int)(k17[k] & 0xffffffffULL);
            float4 c = pts[j];
            float ux = -0.5f * c.x - qx;         // exact original coords
            float uy = -0.5f * c.y - qy;
            float uz = -0.5f * c.z - qz;
            s1x += ux; s1y += uy; s1z += uz;
            cxx += ux * ux; cxy += ux * uy; cxz += ux * uz;
            cyy += uy * uy; cyz += uy * uz; czz += uz * uz;
        }
        const float i16 = 1.0f / 16.0f, i15 = 1.0f / 15.0f;
        float mx = s1x * i16, my = s1y * i16, mz = s1z * i16;
        float c00 = (cxx - 16.0f * mx * mx) * i15;
        float c01 = (cxy - 16.0f * mx * my) * i15;
        float c02 = (cxz - 16.0f * mx * mz) * i15;
        float c11 = (cyy - 16.0f * my * my) * i15;
        float c12 = (cyz - 16.0f * my * mz) * i15;
        float c22 = (czz - 16.0f * mz * mz) * i15;

        float curv = curv_from_cov(c00, c01, c02, c11, c12, c22);

        float v0 = c00 > 0.0f ? c00 : 0.0f;
        float v1 = c11 > 0.0f ? c11 : 0.0f;
        float v2 = c22 > 0.0f ? c22 : 0.0f;

        curv_l[lane] = curv;
        r2l[0][lane] = 1.0f / (0.3f * (1.0f + sqrtf(v0)) + 1e-6f);
        r2l[1][lane] = 1.0f / (0.3f * (1.0f + sqrtf(v1)) + 1e-6f);
        r2l[2][lane] = 1.0f / (0.3f * (1.0f + sqrtf(v2)) + 1e-6f);

        float cs = curv;
        for (int off = 32; off > 0; off >>= 1) cs += __shfl_down(cs, off);
        if (lane == 0) atomicAdd(&ws[WS_CSA + b], cs);
    }

    // ---- device-scope barrier: all 512 blocks co-resident (exact fit) -----
    __syncthreads();                             // wave-0 LDS writes visible
    if (tid == 0) {
        __threadfence();                         // csum/gsum adds ordered
        unsigned* ctr = (unsigned*)ws;
        atomicAdd(ctr, 1u);
        while (atomicAdd(ctr, 0u) < (unsigned)NBLK)
            __builtin_amdgcn_s_sleep(32);
        __threadfence();
        float cmean = atomicAdd(&ws[WS_CSA + b], 0.0f) * (1.0f / 4096.0f);
        float gf    = atomicAdd(&ws[WS_GSA], 0.0f) * (1.0f / 24.0f);
        float denom = 0.3f * (1.0f + gf) + 1e-6f;
        float blend = 1.0f / (1.0f + __expf(-(gf - 0.1f) * 10.0f));
        sc[0] = 1.0f / denom;
        sc[1] = blend;
        sc[2] = 1.0f - blend;
        sc[3] = cmean;
    }
    __syncthreads();

    // ---- phase E: embedding for this block's 64 queries (all from LDS) ----
    {
        int q  = tid >> 3;                       // 0..63
        int j0 = (tid & 7) << 4;                 // 0,16,...,112
        float4 qp = pts[chunk * QPB + q];
        float xq0 = -0.5f * qp.x, xq1 = -0.5f * qp.y, xq2 = -0.5f * qp.z;
        float r20 = r2l[0][q], r21 = r2l[1][q], r22 = r2l[2][q];
        float curv = curv_l[q];
        float w  = 1.0f / (1.0f + __expf(-10.0f * (curv - sc[3])));
        float wc = 1.0f - w;
        float rasig1 = sc[0], blend = sc[1], blendc = sc[2];

        float o[16];
#pragma unroll
        for (int e = 0; e < 16; e++) {
            int j = j0 + e;
            int f = (j < 127) ? j : 128;                  // OUT_IDX
            int d = (f >= 86) ? 2 : ((f >= 43) ? 1 : 0);
            int t = f - d * 43;
            float fv = (float)((double)(t + 1) * (2.0 / 44.0) - 1.0); // FEAT_VAL
            float x  = (d == 0) ? xq0 : ((d == 1) ? xq1 : xq2);
            float r2 = (d == 0) ? r20 : ((d == 1) ? r21 : r22);
            float t1 = (x - fv) * rasig1;
            float e1 = blend * __expf(-0.5f * t1 * t1) + blendc * __cosf(t1);
            float t2 = (x - fv) * r2;
            float e2 = __expf(-0.5f * t2 * t2);
            o[e] = w * e1 + wc * e2;
        }
        float* op = out + ((long)(b * NPTS + chunk * QPB + q) << 7) + j0;
#pragma unroll
        for (int v = 0; v < 4; v++)
            *(float4*)(op + v * 4) = make_float4(o[v * 4], o[v * 4 + 1],
                                                 o[v * 4 + 2], o[v * 4 + 3]);
    }
}

extern "C" void kernel_launch(void* const* d_in, const int* in_sizes, int n_in,
                              void* d_out, int out_size, void* d_ws, size_t ws_size,
                              hipStream_t stream) {
    const float* xyz = (const float*)d_in[0];
    float* out = (float*)d_out;
    float* ws = (float*)d_ws;

    // zero barrier counter + 9 float atomics (graph-captured, per-replay)
    hipMemsetAsync(d_ws, 0, 64, stream);
    fused_kernel<<<NBLK, BLKT, 0, stream>>>(xyz, ws, out);
}

// Round 10
// 246.274 us; speedup vs baseline: 1.1513x; 1.1513x over previous
//
#include <hip/hip_runtime.h>
#include <math.h>

// ---------------------------------------------------------------------------
// EncoderGPECls: kNN(16) -> PCA curvature blend -> adaptive GPE embeddings
// xyz: [8,4096,3] f32  ->  out: [8,4096,128] f32
//
// R22 = R20 (session best, 244.8us) + sched_barrier(0)-pinned LDS pipeline.
//   R21 post-mortem: fusion correct but -39us (barrier tail + spin); revert.
//   R20 clue: VGPR_Count stayed 52 despite depth-8 ping-pong buffers (>=64
//   VGPRs) -> compiler COLLAPSED the pipeline, re-sinking ds_reads to uses;
//   ~3-4 loads in flight vs ~120+cyc contended LDS broadcast latency ->
//   all 4 waves/SIMD stall at lgkmcnt together (issue eff ~25%).
//   Occupancy is LDS-capped at 2 blocks/CU -> VGPRs are FREE up to 128.
//   Fix: __builtin_amdgcn_sched_barrier(0) after each prefetch-load block
//   (pass 1: 8-wide, pass 2: 4-wide). Blocks compute-above-load hoisting
//   (the collapse direction) while leaving compute regions schedulable.
//   Success signature: VGPR -> 90-115. Everything else byte-identical to
//   R20 (exact selection semantics unchanged).
//
// ws float layout:
//   [0, 32768)            curv per point
//   [32768, 131072)       rasig2 (3 SoA planes of 32768)
//   [131072, 131584)      curv partial sums [b][chunk] (8 x 64)
//   [131584, 131680)      per-batch raw sums as 48 DOUBLES
// ---------------------------------------------------------------------------

#define NPTS 4096
#define KNN 17          // 16 neighbors + self (self contributes zero to sums)
#define BLKT 512        // 8 waves; 64 queries per block (1 per lane)
#define QPB 64
#define ESIZE 512       // candidates per wave (eighth)
#define SEG 256         // pass-2 segment size (u8 offsets)
#define SCAP 17         // survivor slots per lane per segment

#define WS_CURV  0
#define WS_RAS2  32768
#define WS_CSUM  131072
#define WS_STAT  131584

typedef unsigned long long ull;
#define SENT 0xFFFFFFFFFFFFFFFFULL

#define SBAR() __builtin_amdgcn_sched_barrier(0)

// THE single d2' definition: explicit fmaf chain, identical IEEE ops at every
// call site. c = (-2cx,-2cy,-2cz,|c|^2), q = original coords.
// d2'(c,q) = |c|^2 - 2 c.q = |c-q|^2 - |q|^2 (per-query constant offset ->
// identical ordering; can be negative). Self always ranks first.
__device__ __forceinline__ float d2p(float4 c, float qx, float qy, float qz) {
    return __builtin_fmaf(c.x, qx, __builtin_fmaf(c.y, qy,
           __builtin_fmaf(c.z, qz, c.w)));
}

// order-preserving u32 encoding of a (possibly negative) float
__device__ __forceinline__ unsigned encf(float f) {
    unsigned u = __float_as_uint(f);
    return u ^ (unsigned)(((int)u >> 31) | 0x80000000u);
}

// predicated replace-max insert of packed (enc(d2')<<32|idx) key
__device__ __forceinline__ void insertp(ull v, bool ins, ull (&md)[KNN],
                                        ull& maxv, int& maxp) {
#pragma unroll
    for (int k = 0; k < KNN; k++) {
        bool sel = ins && (k == maxp);
        md[k] = sel ? v : md[k];
    }
    maxv = md[0]; maxp = 0;
#pragma unroll
    for (int k = 1; k < KNN; k++) {
        bool g = md[k] > maxv;
        maxv = g ? md[k] : maxv;
        maxp = g ? k : maxp;
    }
}

// ---------------- 3x3 symmetric eigensolve (double, trig method) -----------
__device__ __forceinline__ float curv_from_cov(float c00, float c01, float c02,
                                               float c11, float c12, float c22) {
    double a00 = c00, a01 = c01, a02 = c02, a11 = c11, a12 = c12, a22 = c22;
    double tr = a00 + a11 + a22;
    double q  = tr * (1.0 / 3.0);
    double b00 = a00 - q, b11 = a11 - q, b22 = a22 - q;
    double p2 = b00 * b00 + b11 * b11 + b22 * b22
              + 2.0 * (a01 * a01 + a02 * a02 + a12 * a12);
    double lmin;
    if (p2 < 1e-60) {
        lmin = q;
    } else {
        double p  = sqrt(p2 * (1.0 / 6.0));
        double ip = 1.0 / p;
        double m00 = b00 * ip, m11 = b11 * ip, m22 = b22 * ip;
        double m01 = a01 * ip, m02 = a02 * ip, m12 = a12 * ip;
        double det = m00 * (m11 * m22 - m12 * m12)
                   - m01 * (m01 * m22 - m12 * m02)
                   + m02 * (m01 * m12 - m11 * m02);
        double r = 0.5 * det;
        r = r > 1.0 ? 1.0 : (r < -1.0 ? -1.0 : r);
        double phi = acos(r) * (1.0 / 3.0);
        lmin = q + 2.0 * p * cos(phi + 2.0943951023931953);
    }
    return (float)(lmin / (tr + 1e-6));
}

// ---------------- kNN + covariance + curvature + lstd ----------------------
__global__ __launch_bounds__(BLKT, 4) void knn_kernel(const float* __restrict__ xyz,
                                                      float* __restrict__ ws) {
    __shared__ float4 pts[NPTS];                 // 64 KB premultiplied tile
    __shared__ ull aux[1088];                    // 8704 B arena (aliased)
    unsigned char* sbuf = (unsigned char*)aux;   // [SCAP][BLKT] u8 survivors
    unsigned short* pub = (unsigned short*)aux;  // 4 regions x 64x17 u16 idx
    int b = blockIdx.x >> 6;                     // 64 blocks per batch
    int chunk = blockIdx.x & 63;
    int tid = threadIdx.x;
    const float* base = xyz + b * NPTS * 3;
    for (int p = tid; p < NPTS; p += BLKT) {
        float x = base[p * 3], y = base[p * 3 + 1], z = base[p * 3 + 2];
        float w = __builtin_fmaf(z, z, __builtin_fmaf(y, y, x * x));
        pts[p] = make_float4(-2.0f * x, -2.0f * y, -2.0f * z, w);
    }
    __syncthreads();

    // ---- chunk-0 block computes per-batch raw sums in double (into aux) ----
    if (chunk == 0) {
        double sx = 0, sy = 0, sz = 0, qxx = 0, qyy = 0, qzz = 0;
        for (int p = tid; p < NPTS; p += BLKT) {
            float4 c = pts[p];
            float x = -0.5f * c.x, y = -0.5f * c.y, z = -0.5f * c.z; // exact
            sx += (double)x; sy += (double)y; sz += (double)z;
            qxx += (double)x * x; qyy += (double)y * y; qzz += (double)z * z;
        }
        for (int off = 32; off > 0; off >>= 1) {
            sx += __shfl_down(sx, off);  sy += __shfl_down(sy, off);
            sz += __shfl_down(sz, off);  qxx += __shfl_down(qxx, off);
            qyy += __shfl_down(qyy, off); qzz += __shfl_down(qzz, off);
        }
        double* dstat = (double*)aux;
        int wid = tid >> 6;
        if ((tid & 63) == 0) {
            dstat[wid * 6 + 0] = sx;  dstat[wid * 6 + 1] = sy;  dstat[wid * 6 + 2] = sz;
            dstat[wid * 6 + 3] = qxx; dstat[wid * 6 + 4] = qyy; dstat[wid * 6 + 5] = qzz;
        }
        __syncthreads();
        if (tid == 0) {
            double* wd = (double*)(ws + WS_STAT);
            for (int qq = 0; qq < 6; qq++) {
                double a = 0.0;
                for (int w = 0; w < 8; w++) a += dstat[w * 6 + qq];
                wd[b * 6 + qq] = a;
            }
        }
        __syncthreads();                         // aux free for survivor use
    }

    int wv = tid >> 6;                           // wave id: candidate eighth
    int lane = tid & 63;
    int i = chunk * QPB + lane;                  // this lane's query point
    float4 qc = pts[i];
    float qx = -0.5f * qc.x, qy = -0.5f * qc.y, qz = -0.5f * qc.z;  // exact
    int cbase = wv * ESIZE;                      // this wave's candidate range

    // ---- pass 1: med3 top-17 ladder, depth-8 ping-pong, sched-pinned ------
    float md[KNN];
#pragma unroll
    for (int k = 0; k < KNN; k++) md[k] = 3.4e38f;

#define LADDER(c) { \
    float d2 = d2p((c), qx, qy, qz); \
    _Pragma("unroll") \
    for (int k = KNN - 1; k >= 1; k--) \
        md[k] = __builtin_amdgcn_fmed3f(d2, md[k - 1], md[k]); \
    md[0] = fminf(d2, md[0]); }

    {
        float4 A[8], B[8];
#pragma unroll
        for (int u = 0; u < 8; u++) A[u] = pts[cbase + u];
        SBAR();                                  // A-loads issue before use
        for (int m = 0; m < ESIZE - 16; m += 16) {
#pragma unroll
            for (int u = 0; u < 8; u++) B[u] = pts[cbase + m + 8 + u];
            SBAR();                              // B in flight during ladder(A)
#pragma unroll
            for (int u = 0; u < 8; u++) LADDER(A[u]);
#pragma unroll
            for (int u = 0; u < 8; u++) A[u] = pts[cbase + m + 16 + u];
            SBAR();                              // A' in flight during ladder(B)
#pragma unroll
            for (int u = 0; u < 8; u++) LADDER(B[u]);
        }
        // tail: A = [ESIZE-16, ESIZE-8)
#pragma unroll
        for (int u = 0; u < 8; u++) B[u] = pts[cbase + ESIZE - 8 + u];
        SBAR();
#pragma unroll
        for (int u = 0; u < 8; u++) LADDER(A[u]);
#pragma unroll
        for (int u = 0; u < 8; u++) LADDER(B[u]);
    }
#undef LADDER
    float tau = md[KNN - 1];   // exact 17th (identical fmaf chain everywhere)

    // ---- pass 2 (2 segments of 256): u8 survivors, depth-4, sched-pinned --
    ull k17[KNN];
#pragma unroll
    for (int k = 0; k < KNN; k++) k17[k] = SENT;
    ull maxv = SENT; int maxp = 0;

#define P2BODY(c, off) { \
    float d2 = d2p((c), qx, qy, qz); \
    if (d2 <= tau) {                    /* clamp drops latest tie = jax */ \
        if (cnt < SCAP) sbuf[cnt * BLKT + tid] = (unsigned char)(off); \
        cnt++; } }

#pragma unroll
    for (int sgi = 0; sgi < 2; sgi++) {
        int segbase = cbase + sgi * SEG;
        int cnt = 0;
        {
            float4 A[4], B[4];
#pragma unroll
            for (int u = 0; u < 4; u++) A[u] = pts[segbase + u];
            SBAR();
            for (int m = 0; m < SEG - 8; m += 8) {
#pragma unroll
                for (int u = 0; u < 4; u++) B[u] = pts[segbase + m + 4 + u];
                SBAR();
#pragma unroll
                for (int u = 0; u < 4; u++) P2BODY(A[u], m + u);
#pragma unroll
                for (int u = 0; u < 4; u++) A[u] = pts[segbase + m + 8 + u];
                SBAR();
#pragma unroll
                for (int u = 0; u < 4; u++) P2BODY(B[u], m + 4 + u);
            }
#pragma unroll
            for (int u = 0; u < 4; u++) B[u] = pts[segbase + SEG - 4 + u];
            SBAR();
#pragma unroll
            for (int u = 0; u < 4; u++) P2BODY(A[u], SEG - 8 + u);
#pragma unroll
            for (int u = 0; u < 4; u++) P2BODY(B[u], SEG - 4 + u);
        }
        // drain this segment's survivors into the exact u64 top-17
#pragma unroll
        for (int t = 0; t < SCAP; t++) {
            if (__any(t < cnt)) {
                int ix = segbase + sbuf[t * BLKT + tid];
                float4 c = pts[ix];
                float d2 = d2p(c, qx, qy, qz);
                ull key = ((ull)encf(d2) << 32) | (unsigned)ix;
                bool ins = (t < cnt) && (key < maxv);
                if (__any(ins)) insertp(key, ins, k17, maxv, maxp);
            }
        }
    }
#undef P2BODY

    // ---- 3-round tournament merge (u16 idx publish, keys rebuilt exactly) --
    // regions: r * 1088 u16 entries, entry lane*17+k
    __syncthreads();
    if (wv & 1) {
#pragma unroll
        for (int k = 0; k < KNN; k++)
            pub[(wv >> 1) * 1088 + lane * KNN + k] = (unsigned short)(k17[k] & 0xffffULL);
    }
    __syncthreads();
    if (!(wv & 1)) {
        int r = wv >> 1;
#pragma unroll
        for (int k = 0; k < KNN; k++) {
            int ix = pub[r * 1088 + lane * KNN + k];
            float4 c = pts[ix];
            float d2 = d2p(c, qx, qy, qz);
            ull key = ((ull)encf(d2) << 32) | (unsigned)ix;
            bool ins = key < maxv;
            if (__any(ins)) insertp(key, ins, k17, maxv, maxp);
        }
    }
    // round 2: 2->0, 6->4 (regions 0,1)
    __syncthreads();
    if (wv == 2 || wv == 6) {
#pragma unroll
        for (int k = 0; k < KNN; k++)
            pub[(wv >> 2) * 1088 + lane * KNN + k] = (unsigned short)(k17[k] & 0xffffULL);
    }
    __syncthreads();
    if (wv == 0 || wv == 4) {
        int r = wv >> 2;
#pragma unroll
        for (int k = 0; k < KNN; k++) {
            int ix = pub[r * 1088 + lane * KNN + k];
            float4 c = pts[ix];
            float d2 = d2p(c, qx, qy, qz);
            ull key = ((ull)encf(d2) << 32) | (unsigned)ix;
            bool ins = key < maxv;
            if (__any(ins)) insertp(key, ins, k17, maxv, maxp);
        }
    }
    // round 3: 4->0 (region 0)
    __syncthreads();
    if (wv == 4) {
#pragma unroll
        for (int k = 0; k < KNN; k++)
            pub[lane * KNN + k] = (unsigned short)(k17[k] & 0xffffULL);
    }
    __syncthreads();

    // ---- epilogue on wave 0: final merge + moments -> curv, rasig2 --------
    if (wv == 0) {
#pragma unroll
        for (int k = 0; k < KNN; k++) {
            int ix = pub[lane * KNN + k];
            float4 c = pts[ix];
            float d2 = d2p(c, qx, qy, qz);
            ull key = ((ull)encf(d2) << 32) | (unsigned)ix;
            bool ins = key < maxv;
            if (__any(ins)) insertp(key, ins, k17, maxv, maxp);
        }

        float s1x = 0, s1y = 0, s1z = 0;
        float cxx = 0, cxy = 0, cxz = 0, cyy = 0, cyz = 0, czz = 0;
#pragma unroll
        for (int k = 0; k < KNN; k++) {
            int j = (int)(k17[k] & 0xffffffffULL);
            float4 c = pts[j];
            float ux = -0.5f * c.x - qx;         // exact original coords
            float uy = -0.5f * c.y - qy;
            float uz = -0.5f * c.z - qz;
            s1x += ux; s1y += uy; s1z += uz;
            cxx += ux * ux; cxy += ux * uy; cxz += ux * uz;
            cyy += uy * uy; cyz += uy * uz; czz += uz * uz;
        }
        const float i16 = 1.0f / 16.0f, i15 = 1.0f / 15.0f;
        float mx = s1x * i16, my = s1y * i16, mz = s1z * i16;
        float c00 = (cxx - 16.0f * mx * mx) * i15;
        float c01 = (cxy - 16.0f * mx * my) * i15;
        float c02 = (cxz - 16.0f * mx * mz) * i15;
        float c11 = (cyy - 16.0f * my * my) * i15;
        float c12 = (cyz - 16.0f * my * mz) * i15;
        float c22 = (czz - 16.0f * mz * mz) * i15;

        float curv = curv_from_cov(c00, c01, c02, c11, c12, c22);

        float v0 = c00 > 0.0f ? c00 : 0.0f;
        float v1 = c11 > 0.0f ? c11 : 0.0f;
        float v2 = c22 > 0.0f ? c22 : 0.0f;
        float r2x = 1.0f / (0.3f * (1.0f + sqrtf(v0)) + 1e-6f);
        float r2y = 1.0f / (0.3f * (1.0f + sqrtf(v1)) + 1e-6f);
        float r2z = 1.0f / (0.3f * (1.0f + sqrtf(v2)) + 1e-6f);

        int g = b * NPTS + i;
        ws[WS_CURV + g] = curv;
        ws[WS_RAS2 + 0 * 32768 + g] = r2x;
        ws[WS_RAS2 + 1 * 32768 + g] = r2y;
        ws[WS_RAS2 + 2 * 32768 + g] = r2z;

        // non-atomic per-(b,chunk) partial sum
        float cs = curv;
        for (int off = 32; off > 0; off >>= 1) cs += __shfl_down(cs, off);
        if (lane == 0) ws[WS_CSUM + b * 64 + chunk] = cs;
    }
}

// ---------------- final embedding (lean prefix, float4 stores) -------------
__global__ void out_kernel(const float* __restrict__ xyz,
                           const float* __restrict__ ws,
                           float* __restrict__ out) {
    __shared__ float sc[3];                      // rasig1, blend, 1-blend
    __shared__ float scm[8];                     // per-batch curv mean
    if (threadIdx.x < 64) {
        // gstd from double stats (24 lanes) -> sigmoid scalars
        float part = 0.0f;
        if (threadIdx.x < 24) {
            const double* st = (const double*)(ws + WS_STAT);
            int bb = threadIdx.x / 3, dd = threadIdx.x % 3;
            double s = st[bb * 6 + dd], ss = st[bb * 6 + 3 + dd];
            double var = (ss - s * s / 4096.0) / 4095.0;
            part = (float)sqrt(var > 0.0 ? var : 0.0);
        }
        float p2 = part;
        for (int off = 32; off > 0; off >>= 1) p2 += __shfl_down(p2, off);
        if (threadIdx.x == 0) {
            float gf = p2 * (1.0f / 24.0f);
            float denom = 0.3f * (1.0f + gf) + 1e-6f;
            float blend = 1.0f / (1.0f + __expf(-(gf - 0.1f) * 10.0f));
            sc[0] = 1.0f / denom;
            sc[1] = blend;
            sc[2] = 1.0f - blend;
        }
        // per-batch curv means from 512 partials: lane L sums [L*8, L*8+8)
        float cp = 0.0f;
        const float* pf = ws + WS_CSUM;
#pragma unroll
        for (int t = 0; t < 8; t++) cp += pf[threadIdx.x * 8 + t];
        cp += __shfl_down(cp, 4);
        cp += __shfl_down(cp, 2);
        cp += __shfl_down(cp, 1);
        if ((threadIdx.x & 7) == 0) scm[threadIdx.x >> 3] = cp * (1.0f / 4096.0f);
    }
    __syncthreads();

    int q4 = blockIdx.x * 256 + (int)threadIdx.x;     // quad id (4 outputs)
    int j0 = (q4 & 31) << 2;                          // 32 quads per point
    int g  = q4 >> 5;
    int b  = g >> 12;
    float rasig1 = sc[0];
    float blend  = sc[1];
    float blendc = sc[2];
    float curv   = ws[WS_CURV + g];
    float w = 1.0f / (1.0f + __expf(-10.0f * (curv - scm[b])));
    float wc = 1.0f - w;

    float o[4];
#pragma unroll
    for (int e = 0; e < 4; e++) {
        int j = j0 + e;
        int f = (j < 127) ? j : 128;                  // OUT_IDX
        int d = (f >= 86) ? 2 : ((f >= 43) ? 1 : 0);
        int t = f - d * 43;
        float fv = (float)((double)(t + 1) * (2.0 / 44.0) - 1.0);  // FEAT_VAL
        float x = xyz[g * 3 + d];
        float t1 = (x - fv) * rasig1;
        float e1 = blend * __expf(-0.5f * t1 * t1) + blendc * __cosf(t1);
        float t2 = (x - fv) * ws[WS_RAS2 + (d << 15) + g];
        float e2 = __expf(-0.5f * t2 * t2);
        o[e] = w * e1 + wc * e2;
    }
    *(float4*)(out + ((long)q4 << 2)) = make_float4(o[0], o[1], o[2], o[3]);
}

extern "C" void kernel_launch(void* const* d_in, const int* in_sizes, int n_in,
                              void* d_out, int out_size, void* d_ws, size_t ws_size,
                              hipStream_t stream) {
    const float* xyz = (const float*)d_in[0];
    float* out = (float*)d_out;
    float* ws = (float*)d_ws;

    knn_kernel<<<512, BLKT, 0, stream>>>(xyz, ws);
    // each block writes 256 threads x 4 floats = 1024 floats
    out_kernel<<<out_size / 1024, 256, 0, stream>>>(xyz, ws, out);
}